// Round 2
// baseline (652.951 us; speedup 1.0000x reference)
//
#include <hip/hip_runtime.h>

// Ensemble MLP: E=8, B=16384, DS=32, DA=8, H=128, din=40 (padded to 64 for K).
// preds[i,j,b,:] = MLP_j(inp[i,b,:]); out0 = mean_i(preds)+states, out1 = var_i(preds, ddof=1)
//
// R2: __launch_bounds__(256,4) — R1 counters showed latency-bound (MfmaUtil 11%,
// VALUBusy 31%, HBM 14%, Occupancy 22% = 2 blocks/CU) while VGPR=128 and
// LDS=26.6KB both permit 4 blocks/CU. Request the occupancy the kernel can have.

#define NE 8
#define NB 16384
#define DS 32
#define DA 8
#define HH 128
#define DIN 40
#define BT 64            // batch rows per block
#define SIN_STRIDE 72    // 64 + 8 pad (bf16 elements)
#define SH_STRIDE 136    // 128 + 8 pad
#define SLOPE 0.01f

using bf16x8 = __attribute__((ext_vector_type(8))) short;
using f32x4  = __attribute__((ext_vector_type(4))) float;

__device__ __forceinline__ unsigned short f2bf(float f) {
    unsigned int u = __float_as_uint(f);
    u += 0x7FFFu + ((u >> 16) & 1u);
    return (unsigned short)(u >> 16);
}

__device__ __forceinline__ float lrelu(float x) { return x > 0.f ? x : SLOPE * x; }

__global__ __launch_bounds__(256, 4)
void ens_mlp_kernel(const float* __restrict__ states,
                    const float* __restrict__ actions,
                    const float* __restrict__ W0g,
                    const float* __restrict__ b0g,
                    const float* __restrict__ W1g,
                    const float* __restrict__ b1g,
                    const float* __restrict__ W2g,
                    const float* __restrict__ b2g,
                    float* __restrict__ out)
{
    __shared__ __align__(16) unsigned short sIn[BT * SIN_STRIDE];
    __shared__ __align__(16) unsigned short sH[BT * SH_STRIDE];

    const int j    = blockIdx.x & 7;          // j fast-varying: same inp rows hot in L2/L3
    const int bt   = blockIdx.x >> 3;
    const int b0   = bt * BT;
    const int tid  = threadIdx.x;
    const int wave = tid >> 6;
    const int lane = tid & 63;
    const int q    = lane >> 4;               // quad (lane>>4)
    const int l16  = lane & 15;
    const int wn   = wave & 1;                // n-half (64 cols) for layers 0/1
    const int wm   = wave >> 1;               // m-half (32 rows) for layers 0/1

    const float* W0j = W0g + j * (DIN * HH);
    const float* W1j = W1g + j * (HH * HH);
    const float* W2j = W2g + j * (HH * DS);

    // ---- Weight B-fragments into registers (once per block, reused 8x over i) ----
    // B-frag layout (mfma_f32_16x16x32_bf16): lane holds B[k = ks*32 + q*8 + t][n = tile_n + l16]
    bf16x8 w0f[2][4];   // [kstep][ntile]  K=64 (pad), N = 64*wn..+64
    bf16x8 w1f[4][4];   // K=128, N = 64*wn..+64
    bf16x8 w2f[4][2];   // K=128, N = 32 (all waves hold full W2)
    float b0r[4], b1r[4], b2r[2];

    #pragma unroll
    for (int ks = 0; ks < 2; ++ks)
      #pragma unroll
      for (int nt = 0; nt < 4; ++nt) {
        const int n = 64 * wn + nt * 16 + l16;
        #pragma unroll
        for (int t = 0; t < 8; ++t) {
          const int k = ks * 32 + q * 8 + t;
          const float v = (k < DIN) ? W0j[k * HH + n] : 0.f;
          w0f[ks][nt][t] = (short)f2bf(v);
        }
      }
    #pragma unroll
    for (int ks = 0; ks < 4; ++ks)
      #pragma unroll
      for (int nt = 0; nt < 4; ++nt) {
        const int n = 64 * wn + nt * 16 + l16;
        #pragma unroll
        for (int t = 0; t < 8; ++t) {
          const int k = ks * 32 + q * 8 + t;
          w1f[ks][nt][t] = (short)f2bf(W1j[k * HH + n]);
        }
      }
    #pragma unroll
    for (int ks = 0; ks < 4; ++ks)
      #pragma unroll
      for (int nt = 0; nt < 2; ++nt) {
        const int n = nt * 16 + l16;
        #pragma unroll
        for (int t = 0; t < 8; ++t) {
          const int k = ks * 32 + q * 8 + t;
          w2f[ks][nt][t] = (short)f2bf(W2j[k * DS + n]);
        }
      }
    #pragma unroll
    for (int nt = 0; nt < 4; ++nt) {
      b0r[nt] = b0g[j * HH + 64 * wn + nt * 16 + l16];
      b1r[nt] = b1g[j * HH + 64 * wn + nt * 16 + l16];
    }
    #pragma unroll
    for (int nt = 0; nt < 2; ++nt) b2r[nt] = b2g[j * DS + nt * 16 + l16];

    // zero sIn once (cols 40..63 stay zero = K padding; pad cols never read)
    for (int idx = tid; idx < BT * SIN_STRIDE; idx += 256) sIn[idx] = 0;

    float sum[2][4], ssq[2][4];
    #pragma unroll
    for (int nt = 0; nt < 2; ++nt)
      #pragma unroll
      for (int r = 0; r < 4; ++r) { sum[nt][r] = 0.f; ssq[nt][r] = 0.f; }

    const f32x4 z4 = {0.f, 0.f, 0.f, 0.f};

    for (int i = 0; i < NE; ++i) {
        // ---- stage inp[i] tile -> sIn (bf16), cols 0..31 states, 32..39 actions ----
        {
            const float* stp = states  + ((size_t)i * NB + b0) * DS;
            for (int idx = tid; idx < BT * DS; idx += 256) {
                const int r = idx >> 5, c = idx & 31;
                sIn[r * SIN_STRIDE + c] = f2bf(stp[r * DS + c]);
            }
            const float* atp = actions + ((size_t)i * NB + b0) * DA;
            for (int idx = tid; idx < BT * DA; idx += 256) {
                const int r = idx >> 3, c = idx & 7;
                sIn[r * SIN_STRIDE + DS + c] = f2bf(atp[r * DA + c]);
            }
        }
        __syncthreads();   // sIn ready; also fences prev-iter L2 reads of sH

        // ---- Layer 0: h0[64x128] = lrelu(inp @ W0 + b0), K=64 ----
        {
            f32x4 acc[2][4];
            #pragma unroll
            for (int mt = 0; mt < 2; ++mt)
              #pragma unroll
              for (int nt = 0; nt < 4; ++nt) acc[mt][nt] = z4;
            #pragma unroll
            for (int ks = 0; ks < 2; ++ks) {
                bf16x8 a0[2];
                #pragma unroll
                for (int mt = 0; mt < 2; ++mt) {
                    const int row = 32 * wm + 16 * mt + l16;   // A: m = lane&15
                    a0[mt] = *(const bf16x8*)(&sIn[row * SIN_STRIDE + ks * 32 + q * 8]);
                }
                #pragma unroll
                for (int mt = 0; mt < 2; ++mt)
                  #pragma unroll
                  for (int nt = 0; nt < 4; ++nt)
                    acc[mt][nt] = __builtin_amdgcn_mfma_f32_16x16x32_bf16(
                        a0[mt], w0f[ks][nt], acc[mt][nt], 0, 0, 0);
            }
            // bias + leaky + store h0 (C-layout: row = quad*4 + r, col = l16)
            #pragma unroll
            for (int mt = 0; mt < 2; ++mt)
              #pragma unroll
              for (int nt = 0; nt < 4; ++nt) {
                const int col = 64 * wn + nt * 16 + l16;
                #pragma unroll
                for (int r = 0; r < 4; ++r) {
                    const int row = 32 * wm + 16 * mt + q * 4 + r;
                    sH[row * SH_STRIDE + col] = f2bf(lrelu(acc[mt][nt][r] + b0r[nt]));
                }
              }
        }
        __syncthreads();   // h0 ready

        // ---- Layer 1: h1[64x128] = lrelu(h0 @ W1 + b1), K=128 ----
        f32x4 acc1[2][4];
        #pragma unroll
        for (int mt = 0; mt < 2; ++mt)
          #pragma unroll
          for (int nt = 0; nt < 4; ++nt) acc1[mt][nt] = z4;
        #pragma unroll
        for (int ks = 0; ks < 4; ++ks) {
            bf16x8 a1[2];
            #pragma unroll
            for (int mt = 0; mt < 2; ++mt) {
                const int row = 32 * wm + 16 * mt + l16;
                a1[mt] = *(const bf16x8*)(&sH[row * SH_STRIDE + ks * 32 + q * 8]);
            }
            #pragma unroll
            for (int mt = 0; mt < 2; ++mt)
              #pragma unroll
              for (int nt = 0; nt < 4; ++nt)
                acc1[mt][nt] = __builtin_amdgcn_mfma_f32_16x16x32_bf16(
                    a1[mt], w1f[ks][nt], acc1[mt][nt], 0, 0, 0);
        }
        __syncthreads();   // all h0 reads done; sH reusable

        #pragma unroll
        for (int mt = 0; mt < 2; ++mt)
          #pragma unroll
          for (int nt = 0; nt < 4; ++nt) {
            const int col = 64 * wn + nt * 16 + l16;
            #pragma unroll
            for (int r = 0; r < 4; ++r) {
                const int row = 32 * wm + 16 * mt + q * 4 + r;
                sH[row * SH_STRIDE + col] = f2bf(lrelu(acc1[mt][nt][r] + b1r[nt]));
            }
          }
        __syncthreads();   // h1 ready

        // ---- Layer 2: preds[64x32] = h1 @ W2 + b2; accumulate sum/sumsq over i ----
        {
            f32x4 acc2[2];
            acc2[0] = z4; acc2[1] = z4;
            #pragma unroll
            for (int ks = 0; ks < 4; ++ks) {
                const int row = 16 * wave + l16;   // each wave owns 16 rows for L2
                const bf16x8 a2 = *(const bf16x8*)(&sH[row * SH_STRIDE + ks * 32 + q * 8]);
                #pragma unroll
                for (int nt = 0; nt < 2; ++nt)
                    acc2[nt] = __builtin_amdgcn_mfma_f32_16x16x32_bf16(
                        a2, w2f[ks][nt], acc2[nt], 0, 0, 0);
            }
            #pragma unroll
            for (int nt = 0; nt < 2; ++nt)
              #pragma unroll
              for (int r = 0; r < 4; ++r) {
                const float p = acc2[nt][r] + b2r[nt];
                sum[nt][r] += p;
                ssq[nt][r] += p * p;
              }
        }
    }

    // ---- Epilogue: mean + states, unbiased var ----
    #pragma unroll
    for (int nt = 0; nt < 2; ++nt)
      #pragma unroll
      for (int r = 0; r < 4; ++r) {
        const int row = 16 * wave + q * 4 + r;
        const int b   = b0 + row;
        const int col = nt * 16 + l16;
        const size_t o = ((size_t)j * NB + b) * DS + col;
        const float s = sum[nt][r];
        const float mean = s * 0.125f;
        const float var  = (ssq[nt][r] - s * s * 0.125f) * (1.0f / 7.0f);
        out[o] = mean + states[o];                       // next_state_mean (states indexed by j)
        out[(size_t)NE * NB * DS + o] = var;             // var, second output
      }
}

extern "C" void kernel_launch(void* const* d_in, const int* in_sizes, int n_in,
                              void* d_out, int out_size, void* d_ws, size_t ws_size,
                              hipStream_t stream) {
    (void)in_sizes; (void)n_in; (void)d_ws; (void)ws_size; (void)out_size;
    const float* states  = (const float*)d_in[0];
    const float* actions = (const float*)d_in[1];
    const float* W0 = (const float*)d_in[2];
    const float* b0 = (const float*)d_in[3];
    const float* W1 = (const float*)d_in[4];
    const float* b1 = (const float*)d_in[5];
    const float* W2 = (const float*)d_in[6];
    const float* b2 = (const float*)d_in[7];
    float* out = (float*)d_out;
    dim3 grid(NE * (NB / BT));   // 2048 blocks: (j minor, btile major)
    ens_mlp_kernel<<<grid, dim3(256), 0, stream>>>(states, actions, W0, b0, W1, b1, W2, b2, out);
}

// Round 4
// 192.839 us; speedup vs baseline: 3.3860x; 3.3860x over previous
//
#include <hip/hip_runtime.h>

// Ensemble MLP: E=8, B=16384, DS=32, DA=8, H=128, din=40 (padded to 64 for K).
// preds[i,j,b,:] = MLP_j(inp[i,b,:]); out0 = mean_i(preds)+states, out1 = var_i(preds, ddof=1)
//
// R4 = R3 + race fix: sIn zeroing and inp[0] staging are both cross-wave LDS
// scatters to overlapping addresses; R3 had no barrier between them (R2 had the
// same latent race, masked by a longer prologue). Zero at top, barrier before stage.
// R3 design: 32-col weight strips/wave (64 weight VGPRs), (256,3) = 3 blocks/CU
// spill-free, double-buffered sH, 2 barriers per i, input staging overlapped with L1.

#define NE 8
#define NB 16384
#define DS 32
#define DA 8
#define HH 128
#define DIN 40
#define BT 64            // batch rows per block
#define SIN_STRIDE 72    // 64 + 8 pad (bf16 elements)
#define SH_STRIDE 136    // 128 + 8 pad
#define SLOPE 0.01f

using bf16x8 = __attribute__((ext_vector_type(8))) short;
using f32x4  = __attribute__((ext_vector_type(4))) float;

__device__ __forceinline__ unsigned short f2bf(float f) {
    unsigned int u = __float_as_uint(f);
    u += 0x7FFFu + ((u >> 16) & 1u);
    return (unsigned short)(u >> 16);
}

__device__ __forceinline__ float lrelu(float x) { return x > 0.f ? x : SLOPE * x; }

__global__ __launch_bounds__(256, 3)
void ens_mlp_kernel(const float* __restrict__ states,
                    const float* __restrict__ actions,
                    const float* __restrict__ W0g,
                    const float* __restrict__ b0g,
                    const float* __restrict__ W1g,
                    const float* __restrict__ b1g,
                    const float* __restrict__ W2g,
                    const float* __restrict__ b2g,
                    float* __restrict__ out)
{
    __shared__ __align__(16) unsigned short sIn[BT * SIN_STRIDE];
    __shared__ __align__(16) unsigned short sHa[BT * SH_STRIDE];
    __shared__ __align__(16) unsigned short sHb[BT * SH_STRIDE];

    const int j    = blockIdx.x & 7;          // j fast-varying
    const int bt   = blockIdx.x >> 3;
    const int b0   = bt * BT;
    const int tid  = threadIdx.x;
    const int wave = tid >> 6;
    const int lane = tid & 63;
    const int q    = lane >> 4;
    const int l16  = lane & 15;
    const int nb0  = 32 * wave;               // L0/L1: wave owns cols nb0..nb0+31 (all 64 rows)
    const int l2m  = 32 * (wave >> 1);        // L2: wave owns rows l2m..l2m+31
    const int l2n  = 16 * (wave & 1);         //     cols l2n..l2n+15

    // zero sIn FIRST (cols 40..63 stay zero = K padding); the long weight
    // prologue sits between this and the barrier-protected staging below.
    for (int idx = tid; idx < BT * SIN_STRIDE; idx += 256) sIn[idx] = 0;

    const float* W0j = W0g + j * (DIN * HH);
    const float* W1j = W1g + j * (HH * HH);
    const float* W2j = W2g + j * (HH * DS);

    // ---- Weight B-fragments (B[k = ks*32 + q*8 + t][n], n = strip + nt*16 + l16) ----
    bf16x8 w0f[2][2];   // 16 VGPRs
    bf16x8 w1f[4][2];   // 32 VGPRs
    bf16x8 w2f[4];      // 16 VGPRs
    float b0r[2], b1r[2], b2r;

    #pragma unroll
    for (int ks = 0; ks < 2; ++ks)
      #pragma unroll
      for (int nt = 0; nt < 2; ++nt) {
        const int n = nb0 + nt * 16 + l16;
        #pragma unroll
        for (int t = 0; t < 8; ++t) {
          const int k = ks * 32 + q * 8 + t;
          const float v = (k < DIN) ? W0j[k * HH + n] : 0.f;
          w0f[ks][nt][t] = (short)f2bf(v);
        }
      }
    #pragma unroll
    for (int ks = 0; ks < 4; ++ks)
      #pragma unroll
      for (int nt = 0; nt < 2; ++nt) {
        const int n = nb0 + nt * 16 + l16;
        #pragma unroll
        for (int t = 0; t < 8; ++t) {
          const int k = ks * 32 + q * 8 + t;
          w1f[ks][nt][t] = (short)f2bf(W1j[k * HH + n]);
        }
      }
    #pragma unroll
    for (int ks = 0; ks < 4; ++ks) {
        const int n = l2n + l16;
        #pragma unroll
        for (int t = 0; t < 8; ++t) {
          const int k = ks * 32 + q * 8 + t;
          w2f[ks][t] = (short)f2bf(W2j[k * DS + n]);
        }
    }
    #pragma unroll
    for (int nt = 0; nt < 2; ++nt) {
      b0r[nt] = b0g[j * HH + nb0 + nt * 16 + l16];
      b1r[nt] = b1g[j * HH + nb0 + nt * 16 + l16];
    }
    b2r = b2g[j * DS + l2n + l16];

    float sum[2][4], ssq[2][4];
    #pragma unroll
    for (int mt = 0; mt < 2; ++mt)
      #pragma unroll
      for (int r = 0; r < 4; ++r) { sum[mt][r] = 0.f; ssq[mt][r] = 0.f; }

    const f32x4 z4 = {0.f, 0.f, 0.f, 0.f};

    __syncthreads();   // RACE FIX: all zero-writes drained before staging scatters

    // ---- stage inp[0] ----
    {
        const float* stp = states  + ((size_t)0 * NB + b0) * DS;
        for (int idx = tid; idx < BT * DS; idx += 256) {
            const int r = idx >> 5, c = idx & 31;
            sIn[r * SIN_STRIDE + c] = f2bf(stp[r * DS + c]);
        }
        const float* atp = actions + ((size_t)0 * NB + b0) * DA;
        for (int idx = tid; idx < BT * DA; idx += 256) {
            const int r = idx >> 3, c = idx & 7;
            sIn[r * SIN_STRIDE + DS + c] = f2bf(atp[r * DA + c]);
        }
    }
    __syncthreads();

    for (int i = 0; i < NE; ++i) {
        // ---- Layer 0: h0 = lrelu(inp @ W0 + b0), K=64, wave strip 64m x 32n ----
        #pragma unroll
        for (int mh = 0; mh < 2; ++mh) {
            f32x4 acc[2][2];
            #pragma unroll
            for (int mt = 0; mt < 2; ++mt)
              #pragma unroll
              for (int nt = 0; nt < 2; ++nt) acc[mt][nt] = z4;
            #pragma unroll
            for (int ks = 0; ks < 2; ++ks) {
                bf16x8 a0[2];
                #pragma unroll
                for (int mt = 0; mt < 2; ++mt) {
                    const int row = 32 * mh + 16 * mt + l16;
                    a0[mt] = *(const bf16x8*)(&sIn[row * SIN_STRIDE + ks * 32 + q * 8]);
                }
                #pragma unroll
                for (int mt = 0; mt < 2; ++mt)
                  #pragma unroll
                  for (int nt = 0; nt < 2; ++nt)
                    acc[mt][nt] = __builtin_amdgcn_mfma_f32_16x16x32_bf16(
                        a0[mt], w0f[ks][nt], acc[mt][nt], 0, 0, 0);
            }
            #pragma unroll
            for (int mt = 0; mt < 2; ++mt)
              #pragma unroll
              for (int nt = 0; nt < 2; ++nt) {
                const int col = nb0 + nt * 16 + l16;
                #pragma unroll
                for (int r = 0; r < 4; ++r) {
                    const int row = 32 * mh + 16 * mt + q * 4 + r;
                    sHa[row * SH_STRIDE + col] = f2bf(lrelu(acc[mt][nt][r] + b0r[nt]));
                }
              }
        }
        __syncthreads();   // B2: h0 ready; all sIn reads drained (safe to restage)

        // ---- stage inp[i+1] (overlaps L1; sIn free after B2, consumed after B3) ----
        if (i < NE - 1) {
            const float* stp = states  + ((size_t)(i + 1) * NB + b0) * DS;
            for (int idx = tid; idx < BT * DS; idx += 256) {
                const int r = idx >> 5, c = idx & 31;
                sIn[r * SIN_STRIDE + c] = f2bf(stp[r * DS + c]);
            }
            const float* atp = actions + ((size_t)(i + 1) * NB + b0) * DA;
            for (int idx = tid; idx < BT * DA; idx += 256) {
                const int r = idx >> 3, c = idx & 7;
                sIn[r * SIN_STRIDE + DS + c] = f2bf(atp[r * DA + c]);
            }
        }

        // ---- Layer 1: h1 = lrelu(h0 @ W1 + b1), K=128; reads sHa, writes sHb ----
        #pragma unroll
        for (int mh = 0; mh < 2; ++mh) {
            f32x4 acc[2][2];
            #pragma unroll
            for (int mt = 0; mt < 2; ++mt)
              #pragma unroll
              for (int nt = 0; nt < 2; ++nt) acc[mt][nt] = z4;
            #pragma unroll
            for (int ks = 0; ks < 4; ++ks) {
                bf16x8 a1[2];
                #pragma unroll
                for (int mt = 0; mt < 2; ++mt) {
                    const int row = 32 * mh + 16 * mt + l16;
                    a1[mt] = *(const bf16x8*)(&sHa[row * SH_STRIDE + ks * 32 + q * 8]);
                }
                #pragma unroll
                for (int mt = 0; mt < 2; ++mt)
                  #pragma unroll
                  for (int nt = 0; nt < 2; ++nt)
                    acc[mt][nt] = __builtin_amdgcn_mfma_f32_16x16x32_bf16(
                        a1[mt], w1f[ks][nt], acc[mt][nt], 0, 0, 0);
            }
            #pragma unroll
            for (int mt = 0; mt < 2; ++mt)
              #pragma unroll
              for (int nt = 0; nt < 2; ++nt) {
                const int col = nb0 + nt * 16 + l16;
                #pragma unroll
                for (int r = 0; r < 4; ++r) {
                    const int row = 32 * mh + 16 * mt + q * 4 + r;
                    sHb[row * SH_STRIDE + col] = f2bf(lrelu(acc[mt][nt][r] + b1r[nt]));
                }
              }
        }
        __syncthreads();   // B3: h1 + sIn(i+1) ready; sHa writable next iter

        // ---- Layer 2: preds = h1 @ W2 + b2; wave tile 32m x 16n; accumulate ----
        {
            f32x4 acc2[2];
            acc2[0] = z4; acc2[1] = z4;
            #pragma unroll
            for (int ks = 0; ks < 4; ++ks) {
                #pragma unroll
                for (int mt = 0; mt < 2; ++mt) {
                    const int row = l2m + 16 * mt + l16;
                    const bf16x8 a2 = *(const bf16x8*)(&sHb[row * SH_STRIDE + ks * 32 + q * 8]);
                    acc2[mt] = __builtin_amdgcn_mfma_f32_16x16x32_bf16(
                        a2, w2f[ks], acc2[mt], 0, 0, 0);
                }
            }
            #pragma unroll
            for (int mt = 0; mt < 2; ++mt)
              #pragma unroll
              for (int r = 0; r < 4; ++r) {
                const float p = acc2[mt][r] + b2r;
                sum[mt][r] += p;
                ssq[mt][r] += p * p;
              }
        }
        // sHb(i) reads done by all waves before any wave passes B2(i+1), which
        // precedes L1(i+1)'s sHb writes -> safe.
    }

    // ---- Epilogue: mean + states, unbiased var ----
    #pragma unroll
    for (int mt = 0; mt < 2; ++mt)
      #pragma unroll
      for (int r = 0; r < 4; ++r) {
        const int row = l2m + 16 * mt + q * 4 + r;
        const int b   = b0 + row;
        const int col = l2n + l16;
        const size_t o = ((size_t)j * NB + b) * DS + col;
        const float s = sum[mt][r];
        const float mean = s * 0.125f;
        const float var  = (ssq[mt][r] - s * s * 0.125f) * (1.0f / 7.0f);
        out[o] = mean + states[o];
        out[(size_t)NE * NB * DS + o] = var;
      }
}

extern "C" void kernel_launch(void* const* d_in, const int* in_sizes, int n_in,
                              void* d_out, int out_size, void* d_ws, size_t ws_size,
                              hipStream_t stream) {
    (void)in_sizes; (void)n_in; (void)d_ws; (void)ws_size; (void)out_size;
    const float* states  = (const float*)d_in[0];
    const float* actions = (const float*)d_in[1];
    const float* W0 = (const float*)d_in[2];
    const float* b0 = (const float*)d_in[3];
    const float* W1 = (const float*)d_in[4];
    const float* b1 = (const float*)d_in[5];
    const float* W2 = (const float*)d_in[6];
    const float* b2 = (const float*)d_in[7];
    float* out = (float*)d_out;
    dim3 grid(NE * (NB / BT));   // 2048 blocks
    ens_mlp_kernel<<<grid, dim3(256), 0, stream>>>(states, actions, W0, b0, W1, b1, W2, b2, out);
}